// Round 6
// baseline (1302.754 us; speedup 1.0000x reference)
//
#include <hip/hip_runtime.h>

typedef unsigned short u16;
typedef __attribute__((ext_vector_type(8))) short bf16x8;
typedef __attribute__((ext_vector_type(4))) float f32x4;

#define C_    192
#define HW_   65536

__device__ inline u16 f2bf(float f) {
  union { float f; unsigned u; } x; x.f = f;
  unsigned r = x.u + 0x7FFFu + ((x.u >> 16) & 1u);
  return (u16)(r >> 16);
}
__device__ inline float bf2f(u16 s) {
  union { unsigned u; float f; } x; x.u = ((unsigned)s) << 16;
  return x.f;
}

// ---------------- k0: weights fp32 -> bf16, combined qkv bias ----------------
__global__ void k_convert(const float* __restrict__ qkv_w, const float* __restrict__ proj_w,
                          const float* __restrict__ q_bias, const float* __restrict__ v_bias,
                          u16* __restrict__ wq, u16* __restrict__ wp, float* __restrict__ qkvb) {
  int i = blockIdx.x * 256 + threadIdx.x;
  if (i < 110592) wq[i] = f2bf(qkv_w[i]);
  else if (i < 147456) wp[i - 110592] = f2bf(proj_w[i - 110592]);
  else if (i < 148032) {
    int j = i - 147456;
    qkvb[j] = (j < 192) ? q_bias[j] : ((j < 384) ? 0.f : v_bias[j - 384]);
  }
}

// ---------------- k1: CPB MLP table (225 x 8) ----------------
__global__ void k_table(const float* __restrict__ w1, const float* __restrict__ b1,
                        const float* __restrict__ w2, float* __restrict__ table) {
  int row = blockIdx.x;            // 0..224
  int tid = threadIdx.x;
  int a = row / 15, b = row % 15;
  float va = (float)(a - 7) * (8.0f / 7.0f);
  float vb = (float)(b - 7) * (8.0f / 7.0f);
  float c0 = copysignf(log2f(fabsf(va) + 1.0f) * (1.0f / 3.0f), va);
  float c1 = copysignf(log2f(fabsf(vb) + 1.0f) * (1.0f / 3.0f), vb);
  float acc[8];
#pragma unroll
  for (int o = 0; o < 8; ++o) acc[o] = 0.f;
  for (int k = tid; k < 512; k += 256) {
    float h = fmaxf(c0 * w1[k] + c1 * w1[512 + k] + b1[k], 0.f);
#pragma unroll
    for (int o = 0; o < 8; ++o) acc[o] += h * w2[k * 8 + o];
  }
  __shared__ float part[4][8];
  int wave = tid >> 6;
#pragma unroll
  for (int o = 0; o < 8; ++o) {
    float v = acc[o];
    v += __shfl_xor(v, 1, 64);  v += __shfl_xor(v, 2, 64);
    v += __shfl_xor(v, 4, 64);  v += __shfl_xor(v, 8, 64);
    v += __shfl_xor(v, 16, 64); v += __shfl_xor(v, 32, 64);
    acc[o] = v;
  }
  if ((tid & 63) == 0)
#pragma unroll
    for (int o = 0; o < 8; ++o) part[wave][o] = acc[o];
  __syncthreads();
  if (tid < 8)
    table[row * 8 + tid] = part[0][tid] + part[1][tid] + part[2][tid] + part[3][tid];
}

// ---- k2: bias grid, flat = h*4096 + t*64 + g*16 + nt*4 + r;
//      value = bias[h][t][s = nt*16 + g*4 + r] ----
__global__ void k_biasfill(const float* __restrict__ table, float* __restrict__ bias3) {
  int p = blockIdx.x * 256 + threadIdx.x;   // 32768 total
  int h = p >> 12, t = (p >> 6) & 63, g = (p >> 4) & 3, u = p & 15;
  int nt = u >> 2, r = u & 3;
  int s = nt * 16 + g * 4 + r;
  int idx = ((t >> 3) - (s >> 3) + 7) * 15 + ((t & 7) - (s & 7) + 7);
  float v = table[idx * 8 + h];
  bias3[p] = 16.0f / (1.0f + __expf(-v));
}

// ================= pipeline kernel 1: QKV GEMM =================
// one window per block, 4 waves; wave w covers output channels [w*144, w*144+144)
// qkv layout: [win_l*64 + t][576] bf16
__global__ __launch_bounds__(256, 4)
void k_qkv(const float* __restrict__ x, const u16* __restrict__ wq,
           const float* __restrict__ qkvb, u16* __restrict__ qkv, int b0) {
  __shared__ u16 Xl[64 * 200];
  int tid = threadIdx.x;
  int wave = tid >> 6, lane = tid & 63, g = lane >> 4, li = lane & 15;
  int win_l = blockIdx.x;
  int win_g = (b0 << 10) + win_l;
  int b = win_g >> 10, wy = (win_g >> 5) & 31, wx = win_g & 31;
  const float* xb = x + (size_t)b * C_ * HW_;
  int base = (wy * 8) * 256 + wx * 8;
  f32x4 zf = {0.f, 0.f, 0.f, 0.f};

  // stage x -> bf16 LDS [t][c]
#pragma unroll
  for (int it = 0; it < 12; ++it) {
    int i4 = tid + it * 256;                  // 3072 tasks
    int c = i4 >> 4, rem = i4 & 15;
    int ty = rem >> 1, jj = (rem & 1) * 4;
    float4 v = *(const float4*)(xb + c * HW_ + base + ty * 256 + jj);
    int t0 = ty * 8 + jj;
    Xl[(t0 + 0) * 200 + c] = f2bf(v.x);
    Xl[(t0 + 1) * 200 + c] = f2bf(v.y);
    Xl[(t0 + 2) * 200 + c] = f2bf(v.z);
    Xl[(t0 + 3) * 200 + c] = f2bf(v.w);
  }
  __syncthreads();

  u16* qrow = qkv + (size_t)win_l * 64 * 576;
  for (int tb = 0; tb < 4; ++tb) {
    bf16x8 xf[6];
#pragma unroll
    for (int ks = 0; ks < 6; ++ks)
      xf[ks] = *(const bf16x8*)&Xl[(tb * 16 + li) * 200 + ks * 32 + g * 8];
#pragma unroll
    for (int mt = 0; mt < 9; ++mt) {
      int j0 = wave * 144 + mt * 16;
      const u16* wr = wq + (j0 + li) * 192 + g * 8;
      f32x4 a0 = zf, a1 = zf;
#pragma unroll
      for (int ks = 0; ks < 3; ++ks) {
        bf16x8 w0 = *(const bf16x8*)(wr + ks * 32);
        bf16x8 w1 = *(const bf16x8*)(wr + (ks + 3) * 32);
        a0 = __builtin_amdgcn_mfma_f32_16x16x32_bf16(w0, xf[ks], a0, 0, 0, 0);
        a1 = __builtin_amdgcn_mfma_f32_16x16x32_bf16(w1, xf[ks + 3], a1, 0, 0, 0);
      }
      // C: col = li = token, row = j0 + g*4 + r
      f32x4 cb = *(const f32x4*)(qkvb + j0 + g * 4);
      uint2 pk;
      pk.x = f2bf(a0[0] + a1[0] + cb[0]) | ((unsigned)f2bf(a0[1] + a1[1] + cb[1]) << 16);
      pk.y = f2bf(a0[2] + a1[2] + cb[2]) | ((unsigned)f2bf(a0[3] + a1[3] + cb[3]) << 16);
      *(uint2*)&qrow[(tb * 16 + li) * 576 + j0 + g * 4] = pk;
    }
  }
}

// ================= pipeline kernel 2: attention =================
// one wave per (window, head); 8 waves/block = all heads of one window; NO barriers
__global__ __launch_bounds__(512, 2)
void k_attn(const u16* __restrict__ qkv, const float* __restrict__ ls,
            const float* __restrict__ bias3, u16* __restrict__ ao) {
  __shared__ u16 Pl[8 * 1152];
  __shared__ float invk[8 * 64];
  int tid = threadIdx.x, h = tid >> 6, lane = tid & 63, g = lane >> 4, li = lane & 15;
  int win = blockIdx.x;
  const u16* qbase = qkv + (size_t)win * 64 * 576;
  u16* aorow = ao + (size_t)win * 64 * 192;
  bf16x8 z8 = {0, 0, 0, 0, 0, 0, 0, 0};
  f32x4 zf = {0.f, 0.f, 0.f, 0.f};
  float scaleh = __expf(fminf(ls[h], 4.6051702f));

  // q fragments + fused norms (iqr per query token = lane's li)
  bf16x8 qf[4], kf[4];
  float iqr[4];
#pragma unroll
  for (int tb = 0; tb < 4; ++tb) {
    int t = tb * 16 + li;
    qf[tb] = (g < 3) ? *(const bf16x8*)&qbase[t * 576 + h * 24 + g * 8] : z8;
    float p = 0.f;
#pragma unroll
    for (int e = 0; e < 8; ++e) { float v = bf2f((u16)qf[tb][e]); p += v * v; }
    p += __shfl_xor(p, 16, 64);
    p += __shfl_xor(p, 32, 64);
    iqr[tb] = __builtin_amdgcn_rsqf(fmaxf(p, 1e-24f)) * scaleh;
  }
  // k fragments + norms -> LDS (needed in row-permuted order)
#pragma unroll
  for (int nt = 0; nt < 4; ++nt) {
    int t = nt * 16 + li;
    kf[nt] = (g < 3) ? *(const bf16x8*)&qbase[t * 576 + 192 + h * 24 + g * 8] : z8;
    float p = 0.f;
#pragma unroll
    for (int e = 0; e < 8; ++e) { float v = bf2f((u16)kf[nt][e]); p += v * v; }
    p += __shfl_xor(p, 16, 64);
    p += __shfl_xor(p, 32, 64);
    float ik = __builtin_amdgcn_rsqf(fmaxf(p, 1e-24f));
    if (g == 0) invk[h * 64 + t] = ik;
  }
  // v fragments: V^T[d][t] gathered from qkv[t][384 + h*24 + d]
  bf16x8 v0f[2], v1f[2];
#pragma unroll
  for (int ks = 0; ks < 2; ++ks) {
    v0f[ks] = z8; v1f[ks] = z8;
#pragma unroll
    for (int e = 0; e < 8; ++e) {
      int t = ks * 32 + g * 8 + e;
      v0f[ks][e] = (short)qbase[t * 576 + 384 + h * 24 + li];
      if (li < 8) v1f[ks][e] = (short)qbase[t * 576 + 384 + h * 24 + 16 + li];
    }
  }
  f32x4 ik4[4];
#pragma unroll
  for (int nt = 0; nt < 4; ++nt)
    ik4[nt] = *(const f32x4*)&invk[h * 64 + nt * 16 + g * 4];

  u16* Pw = Pl + h * 1152;
#pragma unroll
  for (int tb = 0; tb < 4; ++tb) {
    const float* bp = bias3 + ((h * 64 + tb * 16 + li) << 6) + (g << 4);
    f32x4 bx[4];
#pragma unroll
    for (int nt = 0; nt < 4; ++nt) bx[nt] = *(const f32x4*)(bp + (nt << 2));
    f32x4 s4[4];
#pragma unroll
    for (int nt = 0; nt < 4; ++nt)
      s4[nt] = __builtin_amdgcn_mfma_f32_16x16x32_bf16(kf[nt], qf[tb], zf, 0, 0, 0);
    float iq = iqr[tb];
#pragma unroll
    for (int nt = 0; nt < 4; ++nt)
#pragma unroll
      for (int r = 0; r < 4; ++r)
        s4[nt][r] = s4[nt][r] * iq * ik4[nt][r] + bx[nt][r];
    // softmax over s: 16 local + 2 shfl
    float m = s4[0][0];
#pragma unroll
    for (int nt = 0; nt < 4; ++nt)
#pragma unroll
      for (int r = 0; r < 4; ++r) m = fmaxf(m, s4[nt][r]);
    m = fmaxf(m, __shfl_xor(m, 16, 64));
    m = fmaxf(m, __shfl_xor(m, 32, 64));
    float sum = 0.f;
#pragma unroll
    for (int nt = 0; nt < 4; ++nt)
#pragma unroll
      for (int r = 0; r < 4; ++r) { float e = __expf(s4[nt][r] - m); s4[nt][r] = e; sum += e; }
    sum += __shfl_xor(sum, 16, 64);
    sum += __shfl_xor(sum, 32, 64);
    float is = __builtin_amdgcn_rcpf(sum);
    // P bounce: [t=li][s] b64 stores (unnormalized; 1/sum folded into O)
#pragma unroll
    for (int nt = 0; nt < 4; ++nt) {
      uint2 pk;
      pk.x = f2bf(s4[nt][0]) | ((unsigned)f2bf(s4[nt][1]) << 16);
      pk.y = f2bf(s4[nt][2]) | ((unsigned)f2bf(s4[nt][3]) << 16);
      *(uint2*)&Pw[li * 72 + nt * 16 + g * 4] = pk;
    }
    // PV: O^T = V^T . P^T (same-wave LDS bounce, no barrier)
    f32x4 o0 = zf, o1 = zf;
#pragma unroll
    for (int ks = 0; ks < 2; ++ks) {
      bf16x8 pf = *(const bf16x8*)&Pw[li * 72 + ks * 32 + g * 8];
      o0 = __builtin_amdgcn_mfma_f32_16x16x32_bf16(v0f[ks], pf, o0, 0, 0, 0);
      o1 = __builtin_amdgcn_mfma_f32_16x16x32_bf16(v1f[ks], pf, o1, 0, 0, 0);
    }
    int t = tb * 16 + li;
    {
      uint2 pk;
      pk.x = f2bf(o0[0] * is) | ((unsigned)f2bf(o0[1] * is) << 16);
      pk.y = f2bf(o0[2] * is) | ((unsigned)f2bf(o0[3] * is) << 16);
      *(uint2*)&aorow[t * 192 + h * 24 + g * 4] = pk;
    }
    if (g < 2) {
      uint2 pk;
      pk.x = f2bf(o1[0] * is) | ((unsigned)f2bf(o1[1] * is) << 16);
      pk.y = f2bf(o1[2] * is) | ((unsigned)f2bf(o1[3] * is) << 16);
      *(uint2*)&aorow[t * 192 + h * 24 + 16 + g * 4] = pk;
    }
  }
}

// ================= pipeline kernel 3: proj + residual =================
// block = window-pair (128 tokens), 4 waves, no LDS
__global__ __launch_bounds__(256, 2)
void k_proj(const u16* __restrict__ ao, const float* __restrict__ x,
            const u16* __restrict__ wp, const float* __restrict__ proj_b,
            float* __restrict__ out, int b0) {
  int tid = threadIdx.x, wave = tid >> 6, lane = tid & 63, g = lane >> 4, li = lane & 15;
  int wid = blockIdx.x;
  int b_l = wid >> 9, rem = wid & 511, wy = rem >> 4, wxp = rem & 15;
  int b = b0 + b_l;
  const float* xb = x + (size_t)b * C_ * HW_;
  float* ob = out + (size_t)b * C_ * HW_;
  f32x4 zf = {0.f, 0.f, 0.f, 0.f};
#pragma unroll
  for (int half = 0; half < 2; ++half) {
    int win_l = (b_l << 10) + wy * 32 + wxp * 2 + half;
    const u16* arow = ao + (size_t)win_l * 64 * 192 + (size_t)(wave * 16) * 192;
    bf16x8 af[6];
#pragma unroll
    for (int ks = 0; ks < 6; ++ks)
      af[ks] = *(const bf16x8*)&arow[li * 192 + ks * 32 + g * 8];
    int pxbase = (wy * 8) * 256 + wxp * 16 + half * 8;
    int tl = wave * 16 + g * 4;
    int px = pxbase + (tl >> 3) * 256 + (tl & 7);
#pragma unroll
    for (int nt = 0; nt < 12; ++nt) {
      const u16* wr = wp + (nt * 16 + li) * 192 + g * 8;
      f32x4 a0 = zf, a1 = zf;
#pragma unroll
      for (int ks = 0; ks < 3; ++ks) {
        bf16x8 w0 = *(const bf16x8*)(wr + ks * 32);
        bf16x8 w1 = *(const bf16x8*)(wr + (ks + 3) * 32);
        a0 = __builtin_amdgcn_mfma_f32_16x16x32_bf16(af[ks], w0, a0, 0, 0, 0);
        a1 = __builtin_amdgcn_mfma_f32_16x16x32_bf16(af[ks + 3], w1, a1, 0, 0, 0);
      }
      int c = nt * 16 + li;
      float pb = proj_b[c];
      float4 xv = *(const float4*)(xb + c * HW_ + px);
      float4 r;
      r.x = a0[0] + a1[0] + pb + xv.x;
      r.y = a0[1] + a1[1] + pb + xv.y;
      r.z = a0[2] + a1[2] + pb + xv.z;
      r.w = a0[3] + a1[3] + pb + xv.w;
      *(float4*)(ob + c * HW_ + px) = r;
    }
  }
}

// ================= fallback fused kernel (R5 body, fixed launch bounds) =================
__device__ inline int swzc(int c, int t) {
  return (c & ~63) | ((c & 63) ^ (((t >> 2) & 7) << 3));
}

__global__ __launch_bounds__(512, 2)
void k_fused(const float* __restrict__ x,
             const float* __restrict__ ls, const float* __restrict__ proj_b,
             const u16* __restrict__ wq, const u16* __restrict__ wp,
             const float* __restrict__ qkvb, const float* __restrict__ bias3,
             float* __restrict__ out) {
  __shared__ u16 smem[38400];
  u16* R0 = smem;
  u16* Ar = smem + 12800;
  float* invk_s = (float*)(smem + 37376);
  int tid  = threadIdx.x;
  int wave = tid >> 6, lane = tid & 63, g = lane >> 4, li = lane & 15;
  int tt = wave & 3, half = wave >> 2;
  int bid = blockIdx.x;
  int b = bid >> 10, wy = (bid >> 5) & 31, wx = bid & 31;
  const float* xb = x + (size_t)b * C_ * HW_;
  int base = (wy * 8) * 256 + wx * 8;
  bf16x8 z8 = {0, 0, 0, 0, 0, 0, 0, 0};
  f32x4 zf = {0.f, 0.f, 0.f, 0.f};
  float lsh = ls[wave];
  bf16x8 qw[2][6];
#pragma unroll
  for (int m = 0; m < 2; ++m)
#pragma unroll
    for (int ks = 0; ks < 6; ++ks)
      qw[m][ks] = *(const bf16x8*)(wq + (wave * 24 + m * 16 + li) * 192 + ks * 32 + g * 8);
#pragma unroll
  for (int it = 0; it < 6; ++it) {
    int i4 = tid + it * 512;
    int c = i4 >> 4, rem = i4 & 15;
    int ty = rem >> 1, jj = (rem & 1) * 4;
    float4 v = *(const float4*)(xb + c * HW_ + base + ty * 256 + jj);
    int t0 = ty * 8 + jj;
    int cs = swzc(c, t0);
    R0[(t0 + 0) * 200 + cs] = f2bf(v.x);
    R0[(t0 + 1) * 200 + cs] = f2bf(v.y);
    R0[(t0 + 2) * 200 + cs] = f2bf(v.z);
    R0[(t0 + 3) * 200 + cs] = f2bf(v.w);
  }
  __syncthreads();
  u16* Hq = Ar + wave * 3072;
  u16* Hk = Hq + 1536;
  float scaleh = __expf(fminf(lsh, 4.6051702f));
  float iqr[4];
  bf16x8 qf[4], kf[4];
  {
    f32x4 cb0 = *(const f32x4*)(qkvb + wave * 24 + g * 4);
    f32x4 cb1 = *(const f32x4*)(qkvb + wave * 24 + 16 + g * 4);
#pragma unroll
    for (int tb = 0; tb < 4; ++tb) {
      int t = tb * 16 + li;
      bf16x8 xf[6];
#pragma unroll
      for (int ks = 0; ks < 6; ++ks)
        xf[ks] = *(const bf16x8*)&R0[t * 200 + swzc(ks * 32 + g * 8, t)];
      f32x4 a0 = zf, a1 = zf;
#pragma unroll
      for (int ks = 0; ks < 6; ++ks) {
        a0 = __builtin_amdgcn_mfma_f32_16x16x32_bf16(qw[0][ks], xf[ks], a0, 0, 0, 0);
        a1 = __builtin_amdgcn_mfma_f32_16x16x32_bf16(qw[1][ks], xf[ks], a1, 0, 0, 0);
      }
      float p = 0.f;
#pragma unroll
      for (int r = 0; r < 4; ++r) { a0[r] += cb0[r]; p += a0[r] * a0[r]; }
      if (g < 2) {
#pragma unroll
        for (int r = 0; r < 4; ++r) { a1[r] += cb1[r]; p += a1[r] * a1[r]; }
      }
      p += __shfl_xor(p, 16, 64);
      p += __shfl_xor(p, 32, 64);
      iqr[tb] = __builtin_amdgcn_rsqf(fmaxf(p, 1e-24f)) * scaleh;
      uint2 pk;
      pk.x = f2bf(a0[0]) | ((unsigned)f2bf(a0[1]) << 16);
      pk.y = f2bf(a0[2]) | ((unsigned)f2bf(a0[3]) << 16);
      *(uint2*)&Hq[t * 24 + g * 4] = pk;
      if (g < 2) {
        pk.x = f2bf(a1[0]) | ((unsigned)f2bf(a1[1]) << 16);
        pk.y = f2bf(a1[2]) | ((unsigned)f2bf(a1[3]) << 16);
        *(uint2*)&Hq[t * 24 + 16 + g * 4] = pk;
      }
    }
  }
  {
    bf16x8 kw[2][6];
#pragma unroll
    for (int m = 0; m < 2; ++m)
#pragma unroll
      for (int ks = 0; ks < 6; ++ks)
        kw[m][ks] = *(const bf16x8*)(wq + (192 + wave * 24 + m * 16 + li) * 192 + ks * 32 + g * 8);
    f32x4 cb0 = *(const f32x4*)(qkvb + 192 + wave * 24 + g * 4);
    f32x4 cb1 = *(const f32x4*)(qkvb + 192 + wave * 24 + 16 + g * 4);
#pragma unroll
    for (int nt = 0; nt < 4; ++nt) {
      int t = nt * 16 + li;
      bf16x8 xf[6];
#pragma unroll
      for (int ks = 0; ks < 6; ++ks)
        xf[ks] = *(const bf16x8*)&R0[t * 200 + swzc(ks * 32 + g * 8, t)];
      f32x4 a0 = zf, a1 = zf;
#pragma unroll
      for (int ks = 0; ks < 6; ++ks) {
        a0 = __builtin_amdgcn_mfma_f32_16x16x32_bf16(kw[0][ks], xf[ks], a0, 0, 0, 0);
        a1 = __builtin_amdgcn_mfma_f32_16x16x32_bf16(kw[1][ks], xf[ks], a1, 0, 0, 0);
      }
      float p = 0.f;
#pragma unroll
      for (int r = 0; r < 4; ++r) { a0[r] += cb0[r]; p += a0[r] * a0[r]; }
      if (g < 2) {
#pragma unroll
        for (int r = 0; r < 4; ++r) { a1[r] += cb1[r]; p += a1[r] * a1[r]; }
      }
      p += __shfl_xor(p, 16, 64);
      p += __shfl_xor(p, 32, 64);
      float ik = __builtin_amdgcn_rsqf(fmaxf(p, 1e-24f));
      if (g == 0) invk_s[wave * 64 + t] = ik;
      uint2 pk;
      pk.x = f2bf(a0[0]) | ((unsigned)f2bf(a0[1]) << 16);
      pk.y = f2bf(a0[2]) | ((unsigned)f2bf(a0[3]) << 16);
      *(uint2*)&Hk[t * 24 + g * 4] = pk;
      if (g < 2) {
        pk.x = f2bf(a1[0]) | ((unsigned)f2bf(a1[1]) << 16);
        pk.y = f2bf(a1[2]) | ((unsigned)f2bf(a1[3]) << 16);
        *(uint2*)&Hk[t * 24 + 16 + g * 4] = pk;
      }
    }
  }
#pragma unroll
  for (int tb = 0; tb < 4; ++tb) {
    qf[tb] = (g < 3) ? *(const bf16x8*)&Hq[(tb * 16 + li) * 24 + g * 8] : z8;
    kf[tb] = (g < 3) ? *(const bf16x8*)&Hk[(tb * 16 + li) * 24 + g * 8] : z8;
  }
  __syncthreads();
  u16* vt = smem + 23552;
  {
    bf16x8 xfv[6];
#pragma unroll
    for (int ks = 0; ks < 6; ++ks)
      xfv[ks] = *(const bf16x8*)&R0[(tt * 16 + li) * 200 + swzc(ks * 32 + g * 8, tt * 16 + li)];
#pragma unroll
    for (int it = 0; it < 6; ++it) {
      int jv = half * 96 + it * 16;
      const u16* wr = wq + (384 + jv + li) * 192 + g * 8;
      f32x4 a0 = zf, a1 = zf;
#pragma unroll
      for (int ks = 0; ks < 3; ++ks) {
        bf16x8 w0 = *(const bf16x8*)(wr + ks * 32);
        bf16x8 w1 = *(const bf16x8*)(wr + (ks + 3) * 32);
        a0 = __builtin_amdgcn_mfma_f32_16x16x32_bf16(xfv[ks], w0, a0, 0, 0, 0);
        a1 = __builtin_amdgcn_mfma_f32_16x16x32_bf16(xfv[ks + 3], w1, a1, 0, 0, 0);
      }
      float cb = qkvb[384 + jv + li];
      uint2 pk;
      pk.x = f2bf(a0[0] + a1[0] + cb) | ((unsigned)f2bf(a0[1] + a1[1] + cb) << 16);
      pk.y = f2bf(a0[2] + a1[2] + cb) | ((unsigned)f2bf(a0[3] + a1[3] + cb) << 16);
      *(uint2*)&vt[(jv + li) * 72 + tt * 16 + g * 4] = pk;
    }
  }
  __syncthreads();
  {
    int h = wave;
    bf16x8 v0f[2], v1f[2];
#pragma unroll
    for (int ks = 0; ks < 2; ++ks) {
      v0f[ks] = *(const bf16x8*)&vt[(h * 24 + li) * 72 + ks * 32 + g * 8];
      v1f[ks] = (li < 8) ? *(const bf16x8*)&vt[(h * 24 + 16 + li) * 72 + ks * 32 + g * 8] : z8;
    }
    f32x4 ik4[4];
#pragma unroll
    for (int nt = 0; nt < 4; ++nt)
      ik4[nt] = *(const f32x4*)&invk_s[h * 64 + nt * 16 + g * 4];
    u16* Pw = Ar + wave * 1152;
#pragma unroll
    for (int tb = 0; tb < 4; ++tb) {
      const float* bp = bias3 + ((h * 64 + tb * 16 + li) << 6) + (g << 4);
      f32x4 bx[4];
#pragma unroll
      for (int nt = 0; nt < 4; ++nt) bx[nt] = *(const f32x4*)(bp + (nt << 2));
      f32x4 s4[4];
#pragma unroll
      for (int nt = 0; nt < 4; ++nt)
        s4[nt] = __builtin_amdgcn_mfma_f32_16x16x32_bf16(kf[nt], qf[tb], zf, 0, 0, 0);
      float iq = iqr[tb];
#pragma unroll
      for (int nt = 0; nt < 4; ++nt)
#pragma unroll
        for (int r = 0; r < 4; ++r)
          s4[nt][r] = s4[nt][r] * iq * ik4[nt][r] + bx[nt][r];
      float m = s4[0][0];
#pragma unroll
      for (int nt = 0; nt < 4; ++nt)
#pragma unroll
        for (int r = 0; r < 4; ++r) m = fmaxf(m, s4[nt][r]);
      m = fmaxf(m, __shfl_xor(m, 16, 64));
      m = fmaxf(m, __shfl_xor(m, 32, 64));
      float sum = 0.f;
#pragma unroll
      for (int nt = 0; nt < 4; ++nt)
#pragma unroll
        for (int r = 0; r < 4; ++r) { float e = __expf(s4[nt][r] - m); s4[nt][r] = e; sum += e; }
      sum += __shfl_xor(sum, 16, 64);
      sum += __shfl_xor(sum, 32, 64);
      float is = __builtin_amdgcn_rcpf(sum);
#pragma unroll
      for (int nt = 0; nt < 4; ++nt) {
        uint2 pk;
        pk.x = f2bf(s4[nt][0]) | ((unsigned)f2bf(s4[nt][1]) << 16);
        pk.y = f2bf(s4[nt][2]) | ((unsigned)f2bf(s4[nt][3]) << 16);
        *(uint2*)&Pw[li * 72 + nt * 16 + g * 4] = pk;
      }
      f32x4 o0 = zf, o1 = zf;
#pragma unroll
      for (int ks = 0; ks < 2; ++ks) {
        bf16x8 pf = *(const bf16x8*)&Pw[li * 72 + ks * 32 + g * 8];
        o0 = __builtin_amdgcn_mfma_f32_16x16x32_bf16(v0f[ks], pf, o0, 0, 0, 0);
        o1 = __builtin_amdgcn_mfma_f32_16x16x32_bf16(v1f[ks], pf, o1, 0, 0, 0);
      }
      int t = tb * 16 + li;
      {
        uint2 pk;
        pk.x = f2bf(o0[0] * is) | ((unsigned)f2bf(o0[1] * is) << 16);
        pk.y = f2bf(o0[2] * is) | ((unsigned)f2bf(o0[3] * is) << 16);
        *(uint2*)&R0[t * 200 + h * 24 + g * 4] = pk;
      }
      if (g < 2) {
        uint2 pk;
        pk.x = f2bf(o1[0] * is) | ((unsigned)f2bf(o1[1] * is) << 16);
        pk.y = f2bf(o1[2] * is) | ((unsigned)f2bf(o1[3] * is) << 16);
        *(uint2*)&R0[t * 200 + h * 24 + 16 + g * 4] = pk;
      }
    }
  }
  __syncthreads();
  {
    bf16x8 af[6];
#pragma unroll
    for (int ks = 0; ks < 6; ++ks)
      af[ks] = *(const bf16x8*)&R0[(tt * 16 + li) * 200 + ks * 32 + g * 8];
    u16* obuf = Ar;
#pragma unroll
    for (int it = 0; it < 6; ++it) {
      int ct = half * 96 + it * 16;
      const u16* wr = wp + (ct + li) * 192 + g * 8;
      f32x4 a0 = zf, a1 = zf;
#pragma unroll
      for (int ks = 0; ks < 3; ++ks) {
        bf16x8 w0 = *(const bf16x8*)(wr + ks * 32);
        bf16x8 w1 = *(const bf16x8*)(wr + (ks + 3) * 32);
        a0 = __builtin_amdgcn_mfma_f32_16x16x32_bf16(af[ks], w0, a0, 0, 0, 0);
        a1 = __builtin_amdgcn_mfma_f32_16x16x32_bf16(af[ks + 3], w1, a1, 0, 0, 0);
      }
      float pb = proj_b[ct + li];
      uint2 pk;
      pk.x = f2bf(a0[0] + a1[0] + pb) | ((unsigned)f2bf(a0[1] + a1[1] + pb) << 16);
      pk.y = f2bf(a0[2] + a1[2] + pb) | ((unsigned)f2bf(a0[3] + a1[3] + pb) << 16);
      *(uint2*)&obuf[(ct + li) * 68 + tt * 16 + g * 4] = pk;
    }
  }
  __syncthreads();
  float* ob = out + (size_t)b * C_ * HW_;
#pragma unroll
  for (int it = 0; it < 6; ++it) {
    int i4 = tid + it * 512;
    int c = i4 >> 4, rem = i4 & 15;
    int ty = rem >> 1, jj = (rem & 1) * 4;
    int off = c * HW_ + base + ty * 256 + jj;
    float4 xv = *(const float4*)(xb + off);
    uint2 ov = *(const uint2*)&Ar[c * 68 + ty * 8 + jj];
    float4 r;
    r.x = xv.x + bf2f((u16)(ov.x & 0xFFFFu));
    r.y = xv.y + bf2f((u16)(ov.x >> 16));
    r.z = xv.z + bf2f((u16)(ov.y & 0xFFFFu));
    r.w = xv.w + bf2f((u16)(ov.y >> 16));
    *(float4*)(ob + off) = r;
  }
}

// ---------------- launcher ----------------
extern "C" void kernel_launch(void* const* d_in, const int* in_sizes, int n_in,
                              void* d_out, int out_size, void* d_ws, size_t ws_size,
                              hipStream_t stream) {
  const float* x      = (const float*)d_in[0];
  const float* qkv_w  = (const float*)d_in[2];
  const float* q_bias = (const float*)d_in[3];
  const float* v_bias = (const float*)d_in[4];
  const float* ls     = (const float*)d_in[5];
  const float* w1     = (const float*)d_in[6];
  const float* b1     = (const float*)d_in[7];
  const float* w2     = (const float*)d_in[8];
  const float* proj_w = (const float*)d_in[9];
  const float* proj_b = (const float*)d_in[10];

  char* ws = (char*)d_ws;
  u16*   wq    = (u16*)ws;                         // 221184 B
  u16*   wpv   = wq + 110592;                      // -> 294912
  float* qkvb  = (float*)(ws + 294912);            // -> 297216
  float* bias3 = (float*)(ws + 297216);            // -> 428288
  float* table = (float*)(ws + 428288);            // -> 435488
  float* out   = (float*)d_out;

  hipLaunchKernelGGL(k_convert, dim3(579), dim3(256), 0, stream,
                     qkv_w, proj_w, q_bias, v_bias, wq, wpv, qkvb);
  hipLaunchKernelGGL(k_table, dim3(225), dim3(256), 0, stream, w1, b1, w2, table);
  hipLaunchKernelGGL(k_biasfill, dim3(128), dim3(256), 0, stream, table, bias3);

  const size_t BIG = 1ull << 20;
  const size_t QKV_B = 1024ull * 64 * 576 * 2;     // 75,497,472 per batch
  const size_t AO_B  = 1024ull * 64 * 192 * 2;     // 25,165,824 per batch
  int CB = 0;
  if      (ws_size >= BIG + 4 * (QKV_B + AO_B)) CB = 4;
  else if (ws_size >= BIG + 2 * (QKV_B + AO_B)) CB = 2;
  else if (ws_size >= BIG + 1 * (QKV_B + AO_B)) CB = 1;

  if (CB == 0) {
    hipLaunchKernelGGL(k_fused, dim3(4096), dim3(512), 0, stream,
                       x, ls, proj_b, wq, wpv, qkvb, bias3, out);
    return;
  }
  u16* qkvB = (u16*)(ws + BIG);
  u16* aoB  = (u16*)(ws + BIG + (size_t)CB * QKV_B);
  for (int b0 = 0; b0 < 4; b0 += CB) {
    hipLaunchKernelGGL(k_qkv, dim3(1024 * CB), dim3(256), 0, stream, x, wq, qkvb, qkvB, b0);
    hipLaunchKernelGGL(k_attn, dim3(1024 * CB), dim3(512), 0, stream, qkvB, ls, bias3, aoB);
    hipLaunchKernelGGL(k_proj, dim3(512 * CB), dim3(256), 0, stream, aoB, x, wpv, proj_b, out, b0);
  }
}

// Round 7
// 854.570 us; speedup vs baseline: 1.5245x; 1.5245x over previous
//
#include <hip/hip_runtime.h>

typedef unsigned short u16;
typedef __attribute__((ext_vector_type(8))) short bf16x8;
typedef __attribute__((ext_vector_type(4))) float f32x4;

#define C_    192
#define HW_   65536
#define NWIN  4096

__device__ inline u16 f2bf(float f) {
  union { float f; unsigned u; } x; x.f = f;
  unsigned r = x.u + 0x7FFFu + ((x.u >> 16) & 1u);
  return (u16)(r >> 16);
}
__device__ inline float bf2f(u16 s) {
  union { unsigned u; float f; } x; x.u = ((unsigned)s) << 16;
  return x.f;
}

// ---------------- k0: weights fp32 -> bf16, combined qkv bias ----------------
__global__ void k_convert(const float* __restrict__ qkv_w, const float* __restrict__ proj_w,
                          const float* __restrict__ q_bias, const float* __restrict__ v_bias,
                          u16* __restrict__ wq, u16* __restrict__ wp, float* __restrict__ qkvb) {
  int i = blockIdx.x * 256 + threadIdx.x;
  if (i < 110592) wq[i] = f2bf(qkv_w[i]);
  else if (i < 147456) wp[i - 110592] = f2bf(proj_w[i - 110592]);
  else if (i < 148032) {
    int j = i - 147456;
    qkvb[j] = (j < 192) ? q_bias[j] : ((j < 384) ? 0.f : v_bias[j - 384]);
  }
}

// ---------------- k1: CPB MLP table (225 x 8) ----------------
__global__ void k_table(const float* __restrict__ w1, const float* __restrict__ b1,
                        const float* __restrict__ w2, float* __restrict__ table) {
  int row = blockIdx.x;            // 0..224
  int tid = threadIdx.x;
  int a = row / 15, b = row % 15;
  float va = (float)(a - 7) * (8.0f / 7.0f);
  float vb = (float)(b - 7) * (8.0f / 7.0f);
  float c0 = copysignf(log2f(fabsf(va) + 1.0f) * (1.0f / 3.0f), va);
  float c1 = copysignf(log2f(fabsf(vb) + 1.0f) * (1.0f / 3.0f), vb);
  float acc[8];
#pragma unroll
  for (int o = 0; o < 8; ++o) acc[o] = 0.f;
  for (int k = tid; k < 512; k += 256) {
    float h = fmaxf(c0 * w1[k] + c1 * w1[512 + k] + b1[k], 0.f);
#pragma unroll
    for (int o = 0; o < 8; ++o) acc[o] += h * w2[k * 8 + o];
  }
  __shared__ float part[4][8];
  int wave = tid >> 6;
#pragma unroll
  for (int o = 0; o < 8; ++o) {
    float v = acc[o];
    v += __shfl_xor(v, 1, 64);  v += __shfl_xor(v, 2, 64);
    v += __shfl_xor(v, 4, 64);  v += __shfl_xor(v, 8, 64);
    v += __shfl_xor(v, 16, 64); v += __shfl_xor(v, 32, 64);
    acc[o] = v;
  }
  if ((tid & 63) == 0)
#pragma unroll
    for (int o = 0; o < 8; ++o) part[wave][o] = acc[o];
  __syncthreads();
  if (tid < 8)
    table[row * 8 + tid] = part[0][tid] + part[1][tid] + part[2][tid] + part[3][tid];
}

// ---------------- k2: bias grid, permuted [h][tb][lane][r*4+nt] ----------------
__global__ void k_biasfill(const float* __restrict__ table, float* __restrict__ bias2) {
  int p = blockIdx.x * 256 + threadIdx.x;   // 32768 total
  int h = p >> 12, tb = (p >> 10) & 3, lane = (p >> 4) & 63, u = p & 15;
  int r = u >> 2, nt = u & 3, g = lane >> 4, li = lane & 15;
  int t = tb * 16 + g * 4 + r, s = nt * 16 + li;
  int idx = ((t >> 3) - (s >> 3) + 7) * 15 + ((t & 7) - (s & 7) + 7);
  float v = table[idx * 8 + h];
  bias2[p] = 16.0f / (1.0f + __expf(-v));
}

// -------- one QKV pass: C[64 x 192] slice, wave=(mt, nh) --------
// Software-pipelined weight loads: tile0 preloaded by caller (wpre), tile it+1
// prefetched during tile it's MFMAs. Dual accumulators split the K chain.
template<int PASS>
__device__ inline void qkv_pass(const u16* __restrict__ R0, u16* __restrict__ R1,
                                const u16* __restrict__ wq, const float* __restrict__ qkvb,
                                int mt, int nh, int g, int li, const bf16x8* wpre) {
  f32x4 zf = {0.f, 0.f, 0.f, 0.f};
  bf16x8 af[6];
#pragma unroll
  for (int ks = 0; ks < 6; ++ks)
    af[ks] = *(const bf16x8*)&R0[(mt * 16 + li) * 200 + ks * 32 + g * 8];
  bf16x8 wcur[6], wnxt[6];
#pragma unroll
  for (int ks = 0; ks < 6; ++ks) wcur[ks] = wpre[ks];
#pragma unroll
  for (int it = 0; it < 6; ++it) {
    if (it < 5) {
      const u16* wr = wq + ((size_t)(PASS * 192 + nh * 96 + (it + 1) * 16 + li)) * 192 + g * 8;
#pragma unroll
      for (int ks = 0; ks < 6; ++ks)
        wnxt[ks] = *(const bf16x8*)(wr + ks * 32);
    }
    int j = nh * 96 + it * 16 + li;                 // 0..191 (col within this pass)
    f32x4 a0 = zf, a1 = zf;
#pragma unroll
    for (int ks = 0; ks < 3; ++ks) {
      a0 = __builtin_amdgcn_mfma_f32_16x16x32_bf16(af[ks], wcur[ks], a0, 0, 0, 0);
      a1 = __builtin_amdgcn_mfma_f32_16x16x32_bf16(af[ks + 3], wcur[ks + 3], a1, 0, 0, 0);
    }
    float cb = qkvb[PASS * 192 + j];
    float r0 = a0[0] + a1[0] + cb, r1 = a0[1] + a1[1] + cb;
    float r2 = a0[2] + a1[2] + cb, r3 = a0[3] + a1[3] + cb;
    if (PASS < 2) {                                 // q/k: [t][c], stride 200
      int rb = (mt * 16 + g * 4) * 200 + j;
      R1[rb] = f2bf(r0); R1[rb + 200] = f2bf(r1);
      R1[rb + 400] = f2bf(r2); R1[rb + 600] = f2bf(r3);
    } else {                                        // v: v^T [192][72], packed b64
      uint2 pk;
      pk.x = f2bf(r0) | ((unsigned)f2bf(r1) << 16);
      pk.y = f2bf(r2) | ((unsigned)f2bf(r3) << 16);
      *(uint2*)&R1[j * 72 + mt * 16 + g * 4] = pk;
    }
#pragma unroll
    for (int ks = 0; ks < 6; ++ks) wcur[ks] = wnxt[ks];
  }
}

// ---------------- main fused kernel: 1 window/block, 8 waves, 2 blocks/CU ----------------
__global__ __launch_bounds__(512, 2)
void k_main(const float* __restrict__ x,
            const float* __restrict__ ls, const float* __restrict__ proj_b,
            const u16* __restrict__ wq, const u16* __restrict__ wp,
            const float* __restrict__ qkvb, const float* __restrict__ bias2,
            float* __restrict__ out) {
  __shared__ u16 smem[37888];                 // 75,776 B -> 2 blocks/CU (LDS-capped)
  u16* R0 = smem;                             // [64][200]: x, later ao
  u16* R1 = smem + 12800;                     // q/k staging [64][200]; later v^T [192][72]
  u16* Pl = smem + 26624;                     // 8 x [16][72] per-wave P bounce
  float* invq = (float*)(smem + 35840);       // [8][64] (logit scale folded)
  float* invk = invq + 512;                   // [8][64]
  float* obuf = (float*)(smem + 12800);       // [64][196] fp32, overlays R1+Pl+inv (P5+)

  int tid  = threadIdx.x;
  int wave = tid >> 6, lane = tid & 63, g = lane >> 4, li = lane & 15;
  int mt = wave & 3, nh = wave >> 2;
  int bid = blockIdx.x;
  int b = bid >> 10, wy = (bid >> 5) & 31, wx = bid & 31;
  const float* xb = x + (size_t)b * C_ * HW_;
  int base = (wy * 8) * 256 + wx * 8;
  bf16x8 z8 = {0, 0, 0, 0, 0, 0, 0, 0};

  // prefetch pass-0 (q) weight tile-0: independent of x -> hides under P1's HBM loads
  bf16x8 w0pre[6];
  {
    const u16* wr = wq + ((size_t)(nh * 96 + li)) * 192 + g * 8;
#pragma unroll
    for (int ks = 0; ks < 6; ++ks) w0pre[ks] = *(const bf16x8*)(wr + ks * 32);
  }

  // ---- P1: stage x -> bf16 LDS ----
#pragma unroll
  for (int it = 0; it < 6; ++it) {
    int i4 = tid + it * 512;                  // 3072 tasks
    int c = i4 >> 4, rem = i4 & 15;
    int ty = rem >> 1, jj = (rem & 1) * 4;
    float4 v = *(const float4*)(xb + c * HW_ + base + ty * 256 + jj);
    int t = ty * 8 + jj;
    R0[(t + 0) * 200 + c] = f2bf(v.x);
    R0[(t + 1) * 200 + c] = f2bf(v.y);
    R0[(t + 2) * 200 + c] = f2bf(v.z);
    R0[(t + 3) * 200 + c] = f2bf(v.w);
  }
  __syncthreads();                            // B1

  bf16x8 qf[4], kf[4];

  // ---- P2a: q GEMM ----
  qkv_pass<0>(R0, R1, wq, qkvb, mt, nh, g, li, w0pre);
  __syncthreads();                            // B2

  // prefetch pass-1 (k) tile-0: overlaps P3a's LDS work
  bf16x8 w1pre[6];
  {
    const u16* wr = wq + ((size_t)(192 + nh * 96 + li)) * 192 + g * 8;
#pragma unroll
    for (int ks = 0; ks < 6; ++ks) w1pre[ks] = *(const bf16x8*)(wr + ks * 32);
  }
  // ---- P3a: invq + hoist q-frags (wave = head) ----
  {
    const bf16x8* r8 = (const bf16x8*)&R1[lane * 200 + wave * 24];
    float ssq = 0.f;
#pragma unroll
    for (int ch = 0; ch < 3; ++ch) {
      bf16x8 v8 = r8[ch];
#pragma unroll
      for (int e = 0; e < 8; ++e) { float v = bf2f((u16)v8[e]); ssq += v * v; }
    }
    float inv = __builtin_amdgcn_rsqf(fmaxf(ssq, 1e-24f));
    inv *= __expf(fminf(ls[wave], 4.6051702f));
    invq[wave * 64 + lane] = inv;
#pragma unroll
    for (int tb = 0; tb < 4; ++tb)
      qf[tb] = (g < 3) ? *(const bf16x8*)&R1[(tb * 16 + li) * 200 + wave * 24 + g * 8] : z8;
  }
  __syncthreads();                            // B3

  // ---- P2b: k GEMM ----
  qkv_pass<1>(R0, R1, wq, qkvb, mt, nh, g, li, w1pre);
  __syncthreads();                            // B4

  // prefetch pass-2 (v) tile-0: overlaps P3b
  bf16x8 w2pre[6];
  {
    const u16* wr = wq + ((size_t)(384 + nh * 96 + li)) * 192 + g * 8;
#pragma unroll
    for (int ks = 0; ks < 6; ++ks) w2pre[ks] = *(const bf16x8*)(wr + ks * 32);
  }
  // ---- P3b: invk + hoist k-frags ----
  {
    const bf16x8* r8 = (const bf16x8*)&R1[lane * 200 + wave * 24];
    float ssq = 0.f;
#pragma unroll
    for (int ch = 0; ch < 3; ++ch) {
      bf16x8 v8 = r8[ch];
#pragma unroll
      for (int e = 0; e < 8; ++e) { float v = bf2f((u16)v8[e]); ssq += v * v; }
    }
    invk[wave * 64 + lane] = __builtin_amdgcn_rsqf(fmaxf(ssq, 1e-24f));
#pragma unroll
    for (int nt = 0; nt < 4; ++nt)
      kf[nt] = (g < 3) ? *(const bf16x8*)&R1[(nt * 16 + li) * 200 + wave * 24 + g * 8] : z8;
  }
  __syncthreads();                            // B5

  // ---- P2c: v GEMM -> v^T in R1 ----
  qkv_pass<2>(R0, R1, wq, qkvb, mt, nh, g, li, w2pre);
  __syncthreads();                            // B6 (x in R0 now dead)

  // ---- P4: attention; wave = head; ao -> R0 ----
  {
    int h = wave;
    f32x4 zf = {0.f, 0.f, 0.f, 0.f};
    bf16x8 vf0[2], vf1[2];
#pragma unroll
    for (int ks = 0; ks < 2; ++ks) {
      vf0[ks] = *(const bf16x8*)&R1[(h * 24 + li) * 72 + ks * 32 + g * 8];
      vf1[ks] = (li < 8) ? *(const bf16x8*)&R1[(h * 24 + 16 + li) * 72 + ks * 32 + g * 8] : z8;
    }
    u16* Pw = Pl + wave * 1152;
#pragma unroll
    for (int tb = 0; tb < 4; ++tb) {
      const f32x4* bp = (const f32x4*)(bias2 + (((h * 4 + tb) * 64 + lane) << 4));
      f32x4 bx[4];
#pragma unroll
      for (int r = 0; r < 4; ++r) bx[r] = bp[r];
      f32x4 s4[4];
#pragma unroll
      for (int nt = 0; nt < 4; ++nt) {
        f32x4 z = {0.f, 0.f, 0.f, 0.f};
        s4[nt] = __builtin_amdgcn_mfma_f32_16x16x32_bf16(qf[tb], kf[nt], z, 0, 0, 0);
      }
      f32x4 iq = ((const f32x4*)(invq + h * 64 + tb * 16))[g];
#pragma unroll
      for (int nt = 0; nt < 4; ++nt) {
        float ik = invk[h * 64 + nt * 16 + li];
#pragma unroll
        for (int r = 0; r < 4; ++r)
          s4[nt][r] = s4[nt][r] * iq[r] * ik + bx[r][nt];
      }
#pragma unroll
      for (int r = 0; r < 4; ++r) {
        float m = fmaxf(fmaxf(s4[0][r], s4[1][r]), fmaxf(s4[2][r], s4[3][r]));
        m = fmaxf(m, __shfl_xor(m, 1, 64));
        m = fmaxf(m, __shfl_xor(m, 2, 64));
        m = fmaxf(m, __shfl_xor(m, 4, 64));
        m = fmaxf(m, __shfl_xor(m, 8, 64));
        float sum = 0.f;
#pragma unroll
        for (int nt = 0; nt < 4; ++nt) { float e = __expf(s4[nt][r] - m); s4[nt][r] = e; sum += e; }
        sum += __shfl_xor(sum, 1, 64);
        sum += __shfl_xor(sum, 2, 64);
        sum += __shfl_xor(sum, 4, 64);
        sum += __shfl_xor(sum, 8, 64);
        float is = __builtin_amdgcn_rcpf(sum);
#pragma unroll
        for (int nt = 0; nt < 4; ++nt)
          Pw[(g * 4 + r) * 72 + nt * 16 + li] = f2bf(s4[nt][r] * is);
      }
      // PV: O^T = V^T * P^T (same-wave LDS bounce)
      f32x4 o0 = zf, o1 = zf;
#pragma unroll
      for (int ks = 0; ks < 2; ++ks) {
        bf16x8 pf = *(const bf16x8*)&Pw[li * 72 + ks * 32 + g * 8];
        o0 = __builtin_amdgcn_mfma_f32_16x16x32_bf16(vf0[ks], pf, o0, 0, 0, 0);
        o1 = __builtin_amdgcn_mfma_f32_16x16x32_bf16(vf1[ks], pf, o1, 0, 0, 0);
      }
      int t = tb * 16 + li;
      {
        uint2 pk;
        pk.x = f2bf(o0[0]) | ((unsigned)f2bf(o0[1]) << 16);
        pk.y = f2bf(o0[2]) | ((unsigned)f2bf(o0[3]) << 16);
        *(uint2*)&R0[t * 200 + h * 24 + g * 4] = pk;
      }
      if (g < 2) {
        uint2 pk;
        pk.x = f2bf(o1[0]) | ((unsigned)f2bf(o1[1]) << 16);
        pk.y = f2bf(o1[2]) | ((unsigned)f2bf(o1[3]) << 16);
        *(uint2*)&R0[t * 200 + h * 24 + 16 + g * 4] = pk;
      }
    }
  }
  __syncthreads();                            // B7 (R1/Pl/inv dead -> obuf)

  // ---- P5: proj GEMM from ao (R0) -> obuf fp32 (software-pipelined weights) ----
  {
    f32x4 zf = {0.f, 0.f, 0.f, 0.f};
    bf16x8 wcur[6], wnxt[6];
    {
      const u16* wr = wp + ((size_t)(nh * 96 + li)) * 192 + g * 8;
#pragma unroll
      for (int ks = 0; ks < 6; ++ks) wcur[ks] = *(const bf16x8*)(wr + ks * 32);
    }
    bf16x8 af[6];
#pragma unroll
    for (int ks = 0; ks < 6; ++ks)
      af[ks] = *(const bf16x8*)&R0[(mt * 16 + li) * 200 + ks * 32 + g * 8];
#pragma unroll
    for (int it = 0; it < 6; ++it) {
      if (it < 5) {
        const u16* wr = wp + ((size_t)(nh * 96 + (it + 1) * 16 + li)) * 192 + g * 8;
#pragma unroll
        for (int ks = 0; ks < 6; ++ks) wnxt[ks] = *(const bf16x8*)(wr + ks * 32);
      }
      int j = nh * 96 + it * 16 + li;
      f32x4 a0 = zf, a1 = zf;
#pragma unroll
      for (int ks = 0; ks < 3; ++ks) {
        a0 = __builtin_amdgcn_mfma_f32_16x16x32_bf16(af[ks], wcur[ks], a0, 0, 0, 0);
        a1 = __builtin_amdgcn_mfma_f32_16x16x32_bf16(af[ks + 3], wcur[ks + 3], a1, 0, 0, 0);
      }
      float pb = proj_b[j];
      int rb = (mt * 16 + g * 4) * 196 + j;
      obuf[rb]       = a0[0] + a1[0] + pb;
      obuf[rb + 196] = a0[1] + a1[1] + pb;
      obuf[rb + 392] = a0[2] + a1[2] + pb;
      obuf[rb + 588] = a0[3] + a1[3] + pb;
#pragma unroll
      for (int ks = 0; ks < 6; ++ks) wcur[ks] = wnxt[ks];
    }
  }
  __syncthreads();                            // B8

  // ---- P6: residual (x re-read, batched) + coalesced store ----
  float* ob = out + (size_t)b * C_ * HW_;
  float4 xv[6];
#pragma unroll
  for (int it = 0; it < 6; ++it) {
    int i4 = tid + it * 512;
    int c = i4 >> 4, rem = i4 & 15;
    int ty = rem >> 1, jj = (rem & 1) * 4;
    xv[it] = *(const float4*)(xb + c * HW_ + base + ty * 256 + jj);
  }
#pragma unroll
  for (int it = 0; it < 6; ++it) {
    int i4 = tid + it * 512;
    int c = i4 >> 4, rem = i4 & 15;
    int ty = rem >> 1, jj = (rem & 1) * 4;
    int t = ty * 8 + jj;
    float4 r;
    r.x = xv[it].x + obuf[(t + 0) * 196 + c];
    r.y = xv[it].y + obuf[(t + 1) * 196 + c];
    r.z = xv[it].z + obuf[(t + 2) * 196 + c];
    r.w = xv[it].w + obuf[(t + 3) * 196 + c];
    *(float4*)(ob + c * HW_ + base + (rem >> 1) * 256 + jj) = r;
  }
}

// ---------------- launcher ----------------
extern "C" void kernel_launch(void* const* d_in, const int* in_sizes, int n_in,
                              void* d_out, int out_size, void* d_ws, size_t ws_size,
                              hipStream_t stream) {
  const float* x      = (const float*)d_in[0];
  const float* qkv_w  = (const float*)d_in[2];
  const float* q_bias = (const float*)d_in[3];
  const float* v_bias = (const float*)d_in[4];
  const float* ls     = (const float*)d_in[5];
  const float* w1     = (const float*)d_in[6];
  const float* b1     = (const float*)d_in[7];
  const float* w2     = (const float*)d_in[8];
  const float* proj_w = (const float*)d_in[9];
  const float* proj_b = (const float*)d_in[10];

  u16*   wq    = (u16*)d_ws;                               // 110592 bf16
  u16*   wpv   = wq + 110592;                              // 36864 bf16 -> byte 294912
  float* qkvb  = (float*)((char*)d_ws + 294912);           // 576 f32   -> 297216
  float* bias2 = (float*)((char*)d_ws + 297216);           // 32768 f32 -> 428288
  float* table = (float*)((char*)d_ws + 428288);           // 1800 f32
  float* out   = (float*)d_out;

  hipLaunchKernelGGL(k_convert, dim3(579), dim3(256), 0, stream,
                     qkv_w, proj_w, q_bias, v_bias, wq, wpv, qkvb);
  hipLaunchKernelGGL(k_table, dim3(225), dim3(256), 0, stream, w1, b1, w2, table);
  hipLaunchKernelGGL(k_biasfill, dim3(128), dim3(256), 0, stream, table, bias2);
  hipLaunchKernelGGL(k_main, dim3(NWIN), dim3(512), 0, stream,
                     x, ls, proj_b, wq, wpv, qkvb, bias2, out);
}

// Round 8
// 655.766 us; speedup vs baseline: 1.9866x; 1.3032x over previous
//
#include <hip/hip_runtime.h>

typedef unsigned short u16;
typedef __attribute__((ext_vector_type(8))) short bf16x8;
typedef __attribute__((ext_vector_type(4))) float f32x4;

#define C_    192
#define HW_   65536
#define NWIN  4096

__device__ inline u16 f2bf(float f) {
  union { float f; unsigned u; } x; x.f = f;
  unsigned r = x.u + 0x7FFFu + ((x.u >> 16) & 1u);
  return (u16)(r >> 16);
}
__device__ inline float bf2f(u16 s) {
  union { unsigned u; float f; } x; x.u = ((unsigned)s) << 16;
  return x.f;
}

// ---------------- k0: weights fp32 -> bf16, combined qkv bias ----------------
__global__ void k_convert(const float* __restrict__ qkv_w, const float* __restrict__ proj_w,
                          const float* __restrict__ q_bias, const float* __restrict__ v_bias,
                          u16* __restrict__ wq, u16* __restrict__ wp, float* __restrict__ qkvb) {
  int i = blockIdx.x * 256 + threadIdx.x;
  if (i < 110592) wq[i] = f2bf(qkv_w[i]);
  else if (i < 147456) wp[i - 110592] = f2bf(proj_w[i - 110592]);
  else if (i < 148032) {
    int j = i - 147456;
    qkvb[j] = (j < 192) ? q_bias[j] : ((j < 384) ? 0.f : v_bias[j - 384]);
  }
}

// ---------------- k1: CPB MLP table (225 x 8) ----------------
__global__ void k_table(const float* __restrict__ w1, const float* __restrict__ b1,
                        const float* __restrict__ w2, float* __restrict__ table) {
  int row = blockIdx.x;            // 0..224
  int tid = threadIdx.x;
  int a = row / 15, b = row % 15;
  float va = (float)(a - 7) * (8.0f / 7.0f);
  float vb = (float)(b - 7) * (8.0f / 7.0f);
  float c0 = copysignf(log2f(fabsf(va) + 1.0f) * (1.0f / 3.0f), va);
  float c1 = copysignf(log2f(fabsf(vb) + 1.0f) * (1.0f / 3.0f), vb);
  float acc[8];
#pragma unroll
  for (int o = 0; o < 8; ++o) acc[o] = 0.f;
  for (int k = tid; k < 512; k += 256) {
    float h = fmaxf(c0 * w1[k] + c1 * w1[512 + k] + b1[k], 0.f);
#pragma unroll
    for (int o = 0; o < 8; ++o) acc[o] += h * w2[k * 8 + o];
  }
  __shared__ float part[4][8];
  int wave = tid >> 6;
#pragma unroll
  for (int o = 0; o < 8; ++o) {
    float v = acc[o];
    v += __shfl_xor(v, 1, 64);  v += __shfl_xor(v, 2, 64);
    v += __shfl_xor(v, 4, 64);  v += __shfl_xor(v, 8, 64);
    v += __shfl_xor(v, 16, 64); v += __shfl_xor(v, 32, 64);
    acc[o] = v;
  }
  if ((tid & 63) == 0)
#pragma unroll
    for (int o = 0; o < 8; ++o) part[wave][o] = acc[o];
  __syncthreads();
  if (tid < 8)
    table[row * 8 + tid] = part[0][tid] + part[1][tid] + part[2][tid] + part[3][tid];
}

// ---- k2: bias grid, flat = h*4096 + t*64 + g*16 + nt*4 + r;
//      value = bias[h][query t][key s = nt*16 + g*4 + r] ----
__global__ void k_biasfill(const float* __restrict__ table, float* __restrict__ bias3) {
  int p = blockIdx.x * 256 + threadIdx.x;   // 32768 total
  int h = p >> 12, t = (p >> 6) & 63, g = (p >> 4) & 3, u = p & 15;
  int nt = u >> 2, r = u & 3;
  int s = nt * 16 + g * 4 + r;
  int idx = ((t >> 3) - (s >> 3) + 7) * 15 + ((t & 7) - (s & 7) + 7);
  float v = table[idx * 8 + h];
  bias3[p] = 16.0f / (1.0f + __expf(-v));
}

// ---------------- main fused kernel: 1 window/block, 8 waves, barrier-free middle ----------------
__global__ __launch_bounds__(512, 2)
void k_main(const float* __restrict__ x,
            const float* __restrict__ ls, const float* __restrict__ proj_b,
            const u16* __restrict__ wq, const u16* __restrict__ wp,
            const float* __restrict__ qkvb, const float* __restrict__ bias3,
            float* __restrict__ out) {
  __shared__ u16 smem[38400];                 // 76,800 B -> 2 blocks/CU
  u16* R0 = smem;                             // [64][200]: x, later ao
  u16* Sc = smem + 12800;                     // per-wave scratch: 3072 u16 each (6 KB)
  float* ikw = (float*)(smem + 37376);        // [8][64] inv-k-norms (per-wave region)

  int tid  = threadIdx.x;
  int h = tid >> 6, lane = tid & 63, g = lane >> 4, li = lane & 15;
  int tt = h & 3, half = h >> 2;              // proj-phase roles
  int bid = blockIdx.x;
  int b = bid >> 10, wy = (bid >> 5) & 31, wx = bid & 31;
  const float* xb = x + (size_t)b * C_ * HW_;
  int base = (wy * 8) * 256 + wx * 8;
  bf16x8 z8 = {0, 0, 0, 0, 0, 0, 0, 0};
  f32x4 zf = {0.f, 0.f, 0.f, 0.f};

  // prefetch q-weight fragments for head h (A-operand rows = out-channels).
  // hi-tile rows use (li&7) dup so all loads stay in the q-row range.
  bf16x8 qw0[6], qw1[6];
  {
    const u16* wr0 = wq + (size_t)(h * 24 + li) * 192 + g * 8;
    const u16* wr1 = wq + (size_t)(h * 24 + 16 + (li & 7)) * 192 + g * 8;
#pragma unroll
    for (int ks = 0; ks < 6; ++ks) {
      qw0[ks] = *(const bf16x8*)(wr0 + ks * 32);
      qw1[ks] = *(const bf16x8*)(wr1 + ks * 32);
    }
  }

  // ---- P1: stage x -> bf16 LDS [t][c] ----
#pragma unroll
  for (int it = 0; it < 6; ++it) {
    int i4 = tid + it * 512;                  // 3072 tasks
    int c = i4 >> 4, rem = i4 & 15;
    int ty = rem >> 1, jj = (rem & 1) * 4;
    float4 v = *(const float4*)(xb + c * HW_ + base + ty * 256 + jj);
    int t = ty * 8 + jj;
    R0[(t + 0) * 200 + c] = f2bf(v.x);
    R0[(t + 1) * 200 + c] = f2bf(v.y);
    R0[(t + 2) * 200 + c] = f2bf(v.z);
    R0[(t + 3) * 200 + c] = f2bf(v.w);
  }
  __syncthreads();                            // B1 -- last barrier until proj

  u16* Sw = Sc + h * 3072;                    // this wave's scratch
  u16* Hq = Sw;                               // [64][24]
  u16* Hk = Sw + 1536;                        // [64][24] (live through attention)
  float scaleh = __expf(fminf(ls[h], 4.6051702f));
  float iqr[4];
  bf16x8 qf[4];

  // ---- per-head q GEMM + fused norm (same-wave, no barrier) ----
  {
    f32x4 cb0 = *(const f32x4*)(qkvb + h * 24 + g * 4);
    f32x4 cb1 = *(const f32x4*)(qkvb + h * 24 + 16 + g * 4);   // g>=2 junk, masked
#pragma unroll
    for (int tb = 0; tb < 4; ++tb) {
      int t = tb * 16 + li;
      bf16x8 xf[6];
#pragma unroll
      for (int ks = 0; ks < 6; ++ks)
        xf[ks] = *(const bf16x8*)&R0[t * 200 + ks * 32 + g * 8];
      f32x4 a0 = zf, a1 = zf;
#pragma unroll
      for (int ks = 0; ks < 6; ++ks) {
        a0 = __builtin_amdgcn_mfma_f32_16x16x32_bf16(qw0[ks], xf[ks], a0, 0, 0, 0);
        a1 = __builtin_amdgcn_mfma_f32_16x16x32_bf16(qw1[ks], xf[ks], a1, 0, 0, 0);
      }
      float p = 0.f;
#pragma unroll
      for (int r = 0; r < 4; ++r) { a0[r] += cb0[r]; p += a0[r] * a0[r]; }
      if (g < 2) {
#pragma unroll
        for (int r = 0; r < 4; ++r) { a1[r] += cb1[r]; p += a1[r] * a1[r]; }
      }
      p += __shfl_xor(p, 16, 64);
      p += __shfl_xor(p, 32, 64);
      iqr[tb] = __builtin_amdgcn_rsqf(fmaxf(p, 1e-24f)) * scaleh;
      uint2 pk;
      pk.x = f2bf(a0[0]) | ((unsigned)f2bf(a0[1]) << 16);
      pk.y = f2bf(a0[2]) | ((unsigned)f2bf(a0[3]) << 16);
      *(uint2*)&Hq[t * 24 + g * 4] = pk;
      if (g < 2) {
        pk.x = f2bf(a1[0]) | ((unsigned)f2bf(a1[1]) << 16);
        pk.y = f2bf(a1[2]) | ((unsigned)f2bf(a1[3]) << 16);
        *(uint2*)&Hq[t * 24 + 16 + g * 4] = pk;
      }
    }
#pragma unroll
    for (int tb = 0; tb < 4; ++tb)
      qf[tb] = (g < 3) ? *(const bf16x8*)&Hq[(tb * 16 + li) * 24 + g * 8] : z8;
  }

  // ---- per-head k GEMM + norms (ik -> in-wave LDS; kf stays in Hk) ----
  {
    bf16x8 kw0[6], kw1[6];
    {
      const u16* wr0 = wq + (size_t)(192 + h * 24 + li) * 192 + g * 8;
      const u16* wr1 = wq + (size_t)(192 + h * 24 + 16 + (li & 7)) * 192 + g * 8;
#pragma unroll
      for (int ks = 0; ks < 6; ++ks) {
        kw0[ks] = *(const bf16x8*)(wr0 + ks * 32);
        kw1[ks] = *(const bf16x8*)(wr1 + ks * 32);
      }
    }
    f32x4 cb0 = *(const f32x4*)(qkvb + 192 + h * 24 + g * 4);
    f32x4 cb1 = *(const f32x4*)(qkvb + 192 + h * 24 + 16 + g * 4);
#pragma unroll
    for (int nt = 0; nt < 4; ++nt) {
      int t = nt * 16 + li;
      bf16x8 xf[6];
#pragma unroll
      for (int ks = 0; ks < 6; ++ks)
        xf[ks] = *(const bf16x8*)&R0[t * 200 + ks * 32 + g * 8];
      f32x4 a0 = zf, a1 = zf;
#pragma unroll
      for (int ks = 0; ks < 6; ++ks) {
        a0 = __builtin_amdgcn_mfma_f32_16x16x32_bf16(kw0[ks], xf[ks], a0, 0, 0, 0);
        a1 = __builtin_amdgcn_mfma_f32_16x16x32_bf16(kw1[ks], xf[ks], a1, 0, 0, 0);
      }
      float p = 0.f;
#pragma unroll
      for (int r = 0; r < 4; ++r) { a0[r] += cb0[r]; p += a0[r] * a0[r]; }
      if (g < 2) {
#pragma unroll
        for (int r = 0; r < 4; ++r) { a1[r] += cb1[r]; p += a1[r] * a1[r]; }
      }
      p += __shfl_xor(p, 16, 64);
      p += __shfl_xor(p, 32, 64);
      float ik = __builtin_amdgcn_rsqf(fmaxf(p, 1e-24f));
      if (g == 0) ikw[h * 64 + t] = ik;
      uint2 pk;
      pk.x = f2bf(a0[0]) | ((unsigned)f2bf(a0[1]) << 16);
      pk.y = f2bf(a0[2]) | ((unsigned)f2bf(a0[3]) << 16);
      *(uint2*)&Hk[t * 24 + g * 4] = pk;
      if (g < 2) {
        pk.x = f2bf(a1[0]) | ((unsigned)f2bf(a1[1]) << 16);
        pk.y = f2bf(a1[2]) | ((unsigned)f2bf(a1[3]) << 16);
        *(uint2*)&Hk[t * 24 + 16 + g * 4] = pk;
      }
    }
  }

  // ---- per-head v GEMM -> Hv[d][64] (overlays Hq; in-wave) ----
  u16* Hv = Sw;
  {
    bf16x8 vw0[6], vw1[6];
    {
      const u16* wr0 = wq + (size_t)(384 + h * 24 + li) * 192 + g * 8;
      const u16* wr1 = wq + (size_t)(384 + h * 24 + 16 + (li & 7)) * 192 + g * 8;
#pragma unroll
      for (int ks = 0; ks < 6; ++ks) {
        vw0[ks] = *(const bf16x8*)(wr0 + ks * 32);
        vw1[ks] = *(const bf16x8*)(wr1 + ks * 32);
      }
    }
    float vb0 = qkvb[384 + h * 24 + li];
    float vb1 = qkvb[384 + h * 24 + 16 + (li & 7)];
#pragma unroll
    for (int tb = 0; tb < 4; ++tb) {
      int t = tb * 16 + li;
      bf16x8 xf[6];
#pragma unroll
      for (int ks = 0; ks < 6; ++ks)
        xf[ks] = *(const bf16x8*)&R0[t * 200 + ks * 32 + g * 8];
      f32x4 a0 = zf, a1 = zf;
#pragma unroll
      for (int ks = 0; ks < 6; ++ks) {
        a0 = __builtin_amdgcn_mfma_f32_16x16x32_bf16(xf[ks], vw0[ks], a0, 0, 0, 0);
        a1 = __builtin_amdgcn_mfma_f32_16x16x32_bf16(xf[ks], vw1[ks], a1, 0, 0, 0);
      }
      // C: row = token tb*16+g*4+r, col = d (li for lo, 16+li for hi)
      uint2 pk;
      pk.x = f2bf(a0[0] + vb0) | ((unsigned)f2bf(a0[1] + vb0) << 16);
      pk.y = f2bf(a0[2] + vb0) | ((unsigned)f2bf(a0[3] + vb0) << 16);
      *(uint2*)&Hv[li * 64 + tb * 16 + g * 4] = pk;
      if (li < 8) {
        pk.x = f2bf(a1[0] + vb1) | ((unsigned)f2bf(a1[1] + vb1) << 16);
        pk.y = f2bf(a1[2] + vb1) | ((unsigned)f2bf(a1[3] + vb1) << 16);
        *(uint2*)&Hv[(16 + li) * 64 + tb * 16 + g * 4] = pk;
      }
    }
  }
  // hoist V^T fragments (in-wave; Hv dead after this -> Pw reuses the region)
  bf16x8 vf0[2], vf1[2];
#pragma unroll
  for (int ks = 0; ks < 2; ++ks) {
    vf0[ks] = *(const bf16x8*)&Hv[li * 64 + ks * 32 + g * 8];
    vf1[ks] = (li < 8) ? *(const bf16x8*)&Hv[(16 + li) * 64 + ks * 32 + g * 8] : z8;
  }
  u16* Pw = Sw;                               // [16][72] P bounce (over Hv)

  // ---- attention (no barriers; kf read per-nt from Hk) ----
#pragma unroll
  for (int tb = 0; tb < 4; ++tb) {
    const float* bp = bias3 + ((h * 64 + tb * 16 + li) << 6) + (g << 4);
    f32x4 bx[4];
#pragma unroll
    for (int nt = 0; nt < 4; ++nt) bx[nt] = *(const f32x4*)(bp + (nt << 2));
    f32x4 s4[4];
#pragma unroll
    for (int nt = 0; nt < 4; ++nt) {
      bf16x8 kfn = (g < 3) ? *(const bf16x8*)&Hk[(nt * 16 + li) * 24 + g * 8] : z8;
      s4[nt] = __builtin_amdgcn_mfma_f32_16x16x32_bf16(kfn, qf[tb], zf, 0, 0, 0);
    }
    float iq = iqr[tb];
#pragma unroll
    for (int nt = 0; nt < 4; ++nt) {
      f32x4 ik4 = *(const f32x4*)&ikw[h * 64 + nt * 16 + g * 4];
#pragma unroll
      for (int r = 0; r < 4; ++r)
        s4[nt][r] = s4[nt][r] * iq * ik4[r] + bx[nt][r];
    }
    // softmax over keys: 16 lane-local + 2 shfl
    float m = s4[0][0];
#pragma unroll
    for (int nt = 0; nt < 4; ++nt)
#pragma unroll
      for (int r = 0; r < 4; ++r) m = fmaxf(m, s4[nt][r]);
    m = fmaxf(m, __shfl_xor(m, 16, 64));
    m = fmaxf(m, __shfl_xor(m, 32, 64));
    float sum = 0.f;
#pragma unroll
    for (int nt = 0; nt < 4; ++nt)
#pragma unroll
      for (int r = 0; r < 4; ++r) { float e = __expf(s4[nt][r] - m); s4[nt][r] = e; sum += e; }
    sum += __shfl_xor(sum, 16, 64);
    sum += __shfl_xor(sum, 32, 64);
    float is = __builtin_amdgcn_rcpf(sum);
    // P bounce (unnormalized; 1/sum folded into O)
#pragma unroll
    for (int nt = 0; nt < 4; ++nt) {
      uint2 pk;
      pk.x = f2bf(s4[nt][0]) | ((unsigned)f2bf(s4[nt][1]) << 16);
      pk.y = f2bf(s4[nt][2]) | ((unsigned)f2bf(s4[nt][3]) << 16);
      *(uint2*)&Pw[li * 72 + nt * 16 + g * 4] = pk;
    }
    // PV: O^T = V^T . P^T
    f32x4 o0 = zf, o1 = zf;
#pragma unroll
    for (int ks = 0; ks < 2; ++ks) {
      bf16x8 pf = *(const bf16x8*)&Pw[li * 72 + ks * 32 + g * 8];
      o0 = __builtin_amdgcn_mfma_f32_16x16x32_bf16(vf0[ks], pf, o0, 0, 0, 0);
      o1 = __builtin_amdgcn_mfma_f32_16x16x32_bf16(vf1[ks], pf, o1, 0, 0, 0);
    }
    int t = tb * 16 + li;
    {
      uint2 pk;
      pk.x = f2bf(o0[0] * is) | ((unsigned)f2bf(o0[1] * is) << 16);
      pk.y = f2bf(o0[2] * is) | ((unsigned)f2bf(o0[3] * is) << 16);
      *(uint2*)&R0[t * 200 + h * 24 + g * 4] = pk;
    }
    if (g < 2) {
      uint2 pk;
      pk.x = f2bf(o1[0] * is) | ((unsigned)f2bf(o1[1] * is) << 16);
      pk.y = f2bf(o1[2] * is) | ((unsigned)f2bf(o1[3] * is) << 16);
      *(uint2*)&R0[t * 200 + h * 24 + 16 + g * 4] = pk;
    }
  }
  __syncthreads();                            // B2 (ao complete)

  // ---- P5: proj, O = ao . Wp^T -> obuf bf16 [192][68] ----
  u16* obuf = smem + 12800;                   // overlays all wave scratch
  {
    bf16x8 af[6];
#pragma unroll
    for (int ks = 0; ks < 6; ++ks)
      af[ks] = *(const bf16x8*)&R0[(tt * 16 + li) * 200 + ks * 32 + g * 8];
#pragma unroll
    for (int it = 0; it < 6; ++it) {
      int ct = half * 96 + it * 16;
      const u16* wr = wp + (ct + li) * 192 + g * 8;
      f32x4 a0 = zf, a1 = zf;
#pragma unroll
      for (int ks = 0; ks < 3; ++ks) {
        bf16x8 w0 = *(const bf16x8*)(wr + ks * 32);
        bf16x8 w1 = *(const bf16x8*)(wr + (ks + 3) * 32);
        a0 = __builtin_amdgcn_mfma_f32_16x16x32_bf16(af[ks], w0, a0, 0, 0, 0);
        a1 = __builtin_amdgcn_mfma_f32_16x16x32_bf16(af[ks + 3], w1, a1, 0, 0, 0);
      }
      float pb = proj_b[ct + li];
      uint2 pk;
      pk.x = f2bf(a0[0] + a1[0] + pb) | ((unsigned)f2bf(a0[1] + a1[1] + pb) << 16);
      pk.y = f2bf(a0[2] + a1[2] + pb) | ((unsigned)f2bf(a0[3] + a1[3] + pb) << 16);
      *(uint2*)&obuf[(ct + li) * 68 + tt * 16 + g * 4] = pk;
    }
  }
  __syncthreads();                            // B3

  // ---- P6: residual (x re-read) + b64 obuf reads + coalesced store ----
  float* ob = out + (size_t)b * C_ * HW_;
  float4 xv[6];
#pragma unroll
  for (int it = 0; it < 6; ++it) {
    int i4 = tid + it * 512;
    int c = i4 >> 4, rem = i4 & 15;
    int ty = rem >> 1, jj = (rem & 1) * 4;
    xv[it] = *(const float4*)(xb + c * HW_ + base + ty * 256 + jj);
  }
  uint2 ov[6];
#pragma unroll
  for (int it = 0; it < 6; ++it) {
    int i4 = tid + it * 512;
    int c = i4 >> 4, rem = i4 & 15;
    int ty = rem >> 1, jj = (rem & 1) * 4;
    ov[it] = *(const uint2*)&obuf[c * 68 + ty * 8 + jj];
  }
#pragma unroll
  for (int it = 0; it < 6; ++it) {
    int i4 = tid + it * 512;
    int c = i4 >> 4, rem = i4 & 15;
    int ty = rem >> 1, jj = (rem & 1) * 4;
    float4 r;
    r.x = xv[it].x + bf2f((u16)(ov[it].x & 0xFFFFu));
    r.y = xv[it].y + bf2f((u16)(ov[it].x >> 16));
    r.z = xv[it].z + bf2f((u16)(ov[it].y & 0xFFFFu));
    r.w = xv[it].w + bf2f((u16)(ov[it].y >> 16));
    *(float4*)(ob + c * HW_ + base + ty * 256 + jj) = r;
  }
}

// ---------------- launcher ----------------
extern "C" void kernel_launch(void* const* d_in, const int* in_sizes, int n_in,
                              void* d_out, int out_size, void* d_ws, size_t ws_size,
                              hipStream_t stream) {
  const float* x      = (const float*)d_in[0];
  const float* qkv_w  = (const float*)d_in[2];
  const float* q_bias = (const float*)d_in[3];
  const float* v_bias = (const float*)d_in[4];
  const float* ls     = (const float*)d_in[5];
  const float* w1     = (const float*)d_in[6];
  const float* b1     = (const float*)d_in[7];
  const float* w2     = (const float*)d_in[8];
  const float* proj_w = (const float*)d_in[9];
  const float* proj_b = (const float*)d_in[10];

  u16*   wq    = (u16*)d_ws;                               // 110592 bf16
  u16*   wpv   = wq + 110592;                              // 36864 bf16 -> byte 294912
  float* qkvb  = (float*)((char*)d_ws + 294912);           // 576 f32   -> 297216
  float* bias3 = (float*)((char*)d_ws + 297216);           // 32768 f32 -> 428288
  float* table = (float*)((char*)d_ws + 428288);           // 1800 f32
  float* out   = (float*)d_out;

  hipLaunchKernelGGL(k_convert, dim3(579), dim3(256), 0, stream,
                     qkv_w, proj_w, q_bias, v_bias, wq, wpv, qkvb);
  hipLaunchKernelGGL(k_table, dim3(225), dim3(256), 0, stream, w1, b1, w2, table);
  hipLaunchKernelGGL(k_biasfill, dim3(128), dim3(256), 0, stream, table, bias3);
  hipLaunchKernelGGL(k_main, dim3(NWIN), dim3(512), 0, stream,
                     x, ls, proj_b, wq, wpv, qkvb, bias3, out);
}